// Round 1
// baseline (174.907 us; speedup 1.0000x reference)
//
#include <hip/hip_runtime.h>
#include <stdint.h>

// ---------------------------------------------------------------------------
// TemporalCrossAttention: x[2048,16,512] -> out[2048,16,512] (fp32 in/out)
// Pipeline: cast x->bf16 | transpose W->B^T bf16 | GEMM qkv | attn (MFMA) | GEMM out
// Workspace layout (bytes):
//   [0, 100663296)            qkv bf16 [32768][1536]
//   [100663296, 134217728)    x_bf16 [32768][512]  (reused as attn_out after GEMM1)
//   [134217728, 135790592)    WqkvT bf16 [1536][512]
//   [135790592, 136314880)    WoT   bf16 [512][512]
// ---------------------------------------------------------------------------

using bf16x8 = __attribute__((ext_vector_type(8))) short;
using f32x4  = __attribute__((ext_vector_type(4))) float;

#define AS3P(p) ((__attribute__((address_space(3))) void*)(p))
#define AS1P(p) ((const __attribute__((address_space(1))) void*)(p))

__device__ __forceinline__ float bf2f(uint16_t u) {
  unsigned int x = ((unsigned int)u) << 16;
  return __builtin_bit_cast(float, x);
}
__device__ __forceinline__ uint16_t f2bf(float f) {
  unsigned int x = __builtin_bit_cast(unsigned int, f);
  x += 0x7fffu + ((x >> 16) & 1u);
  return (uint16_t)(x >> 16);
}

// ---------------- cast x fp32 -> bf16 (8 elems/thread) ----------------
__global__ void cast_kernel(const float* __restrict__ in, uint16_t* __restrict__ out, int n8) {
  int i = blockIdx.x * 256 + threadIdx.x;
  if (i >= n8) return;
  float4 a = ((const float4*)in)[i * 2];
  float4 b = ((const float4*)in)[i * 2 + 1];
  uint4 r;
  r.x = (uint32_t)f2bf(a.x) | ((uint32_t)f2bf(a.y) << 16);
  r.y = (uint32_t)f2bf(a.z) | ((uint32_t)f2bf(a.w) << 16);
  r.z = (uint32_t)f2bf(b.x) | ((uint32_t)f2bf(b.y) << 16);
  r.w = (uint32_t)f2bf(b.z) | ((uint32_t)f2bf(b.w) << 16);
  ((uint4*)out)[i] = r;
}

// ------------- transpose-cast [512][512] f32 -> dst[n][k]=src[k][n] bf16 -------------
__global__ void transpose_cast(const float* __restrict__ src, uint16_t* __restrict__ dst) {
  __shared__ float tile[32][33];
  int tx = threadIdx.x, ty = threadIdx.y;           // (32,8)
  int c0 = blockIdx.x * 32, r0 = blockIdx.y * 32;
  #pragma unroll
  for (int k = 0; k < 4; ++k)
    tile[ty + 8 * k][tx] = src[(r0 + ty + 8 * k) * 512 + c0 + tx];
  __syncthreads();
  #pragma unroll
  for (int k = 0; k < 4; ++k)
    dst[(c0 + ty + 8 * k) * 512 + r0 + tx] = f2bf(tile[tx][ty + 8 * k]);
}

// ---------------- GEMM: C[M,N] = A[M,K] * B_T[N,K]^T  (bf16 in, m97 structure) ----------------
// 128x128 tile, BK=32, 4 waves (each a 64x64 quadrant of 4x4 16x16x32 MFMAs),
// global_load_lds width-16 staging, 2 barriers per K-step.
template<int OUT_BF16>
__global__ __launch_bounds__(256) void gemm_bt(
    const uint16_t* __restrict__ A, const uint16_t* __restrict__ B,
    void* __restrict__ C, const float* __restrict__ bias,
    int M, int N, int K) {
  __shared__ __align__(16) uint16_t sA[128 * 32];
  __shared__ __align__(16) uint16_t sB[128 * 32];
  const int tid = threadIdx.x;
  const int w = tid >> 6, l = tid & 63;
  const int nBase = blockIdx.x * 128;
  const int mBase = blockIdx.y * 128;
  const int wr = (w >> 1) * 64, wc = (w & 1) * 64;
  const int lr = l & 15, kc = l >> 4;
  f32x4 acc[4][4] = {};
  // staging: wave w, call i covers 16 rows: row = w*32 + i*16 + l/4, kcol = (l&3)*8
  const int sRow = w * 32 + (l >> 2);
  const int sK = (l & 3) * 8;
  const uint16_t* gA = A + (size_t)(mBase + sRow) * K + sK;
  const uint16_t* gB = B + (size_t)(nBase + sRow) * K + sK;
  uint16_t* lA = sA + w * 1024;  // wave-uniform LDS base (HW adds lane*16B)
  uint16_t* lB = sB + w * 1024;
  for (int kt = 0; kt < K; kt += 32) {
    __builtin_amdgcn_global_load_lds(AS1P(gA),          AS3P(lA),       16, 0, 0);
    __builtin_amdgcn_global_load_lds(AS1P(gA + 16 * K), AS3P(lA + 512), 16, 0, 0);
    __builtin_amdgcn_global_load_lds(AS1P(gB),          AS3P(lB),       16, 0, 0);
    __builtin_amdgcn_global_load_lds(AS1P(gB + 16 * K), AS3P(lB + 512), 16, 0, 0);
    gA += 32; gB += 32;
    __syncthreads();   // compiler drains vmcnt(0) before s_barrier -> staged data visible
    bf16x8 af[4], bfr[4];
    #pragma unroll
    for (int m = 0; m < 4; ++m)
      af[m] = *(const bf16x8*)(sA + (wr + m * 16 + lr) * 32 + kc * 8);
    #pragma unroll
    for (int n = 0; n < 4; ++n)
      bfr[n] = *(const bf16x8*)(sB + (wc + n * 16 + lr) * 32 + kc * 8);
    #pragma unroll
    for (int m = 0; m < 4; ++m)
      #pragma unroll
      for (int n = 0; n < 4; ++n)
        acc[m][n] = __builtin_amdgcn_mfma_f32_16x16x32_bf16(af[m], bfr[n], acc[m][n], 0, 0, 0);
    __syncthreads();   // protect LDS before next-iter staging
  }
  // epilogue: C/D layout col = lane&15, row = (lane>>4)*4 + reg  [measured m89/m91]
  #pragma unroll
  for (int m = 0; m < 4; ++m)
    #pragma unroll
    for (int n = 0; n < 4; ++n) {
      const int col = nBase + wc + n * 16 + lr;
      #pragma unroll
      for (int r = 0; r < 4; ++r) {
        const int row = mBase + wr + m * 16 + kc * 4 + r;
        const float v = acc[m][n][r];
        if (OUT_BF16) ((uint16_t*)C)[(size_t)row * N + col] = f2bf(v);
        else          ((float*)C)[(size_t)row * N + col]    = v + bias[col];
      }
    }
}

// ---------------- attention: one wave per (b,h) ----------------
// sim = (q k^T + q relk^T gathered at j=s-t+16) * scale ; softmax over s (16-lane shuffle)
// out = attn @ v + w2 @ relv  where w2[t][j] = attn[t][j+t-16] (j in [0,32); cols 0,32 are 0)
__global__ __launch_bounds__(256) void attn_kernel(
    const uint16_t* __restrict__ qkv,
    const float* __restrict__ relk, const float* __restrict__ relv,
    uint16_t* __restrict__ outA) {
  __shared__ __align__(16) uint16_t relkS[33 * 72];     // relk[j][d], row stride 72 (16B-aligned rows)
  __shared__ __align__(16) uint16_t relvT[64 * 40];     // relvT[d][j] = relv[j][d]
  __shared__ __align__(16) uint16_t vT[4][64 * 24];     // per-wave vT[d][s] = v[s][d]
  __shared__ float attnS[4][16 * 17];                   // per-wave attn[t][s], padded
  const int tid = threadIdx.x;
  for (int e = tid; e < 33 * 64; e += 256) {
    int j = e >> 6, d = e & 63;
    relkS[j * 72 + d] = f2bf(relk[e]);
    relvT[d * 40 + j] = f2bf(relv[e]);
  }
  const int w = tid >> 6, l = tid & 63;
  const int bh = blockIdx.x * 4 + w;
  const int b = bh >> 3, h = bh & 7;
  const int rowBase = b * 16;
  const int lr = l & 15, kc = l >> 4;
  // q (A-frag: row t = lane&15) and k (B-frag: col s = lane&15), d-contiguous 8 per lane
  const uint16_t* qrow = qkv + (size_t)(rowBase + lr) * 1536 + h * 64;
  bf16x8 aq0 = *(const bf16x8*)(qrow + kc * 8);
  bf16x8 aq1 = *(const bf16x8*)(qrow + 32 + kc * 8);
  const uint16_t* krow = qrow + 512;
  bf16x8 bk0 = *(const bf16x8*)(krow + kc * 8);
  bf16x8 bk1 = *(const bf16x8*)(krow + 32 + kc * 8);
  // stage vT (per-wave): lane loads v[s][dg*16..+15], writes transposed
  {
    const int s = l >> 2, dg = l & 3;
    const uint16_t* vrow = qkv + (size_t)(rowBase + s) * 1536 + 1024 + h * 64 + dg * 16;
    uint4 v0 = *(const uint4*)vrow;
    uint4 v1 = *(const uint4*)(vrow + 8);
    uint16_t tmp[16];
    *(uint4*)(tmp) = v0; *(uint4*)(tmp + 8) = v1;
    #pragma unroll
    for (int i = 0; i < 16; ++i)
      vT[w][(dg * 16 + i) * 24 + s] = tmp[i];
  }
  __syncthreads();
  const f32x4 zero = {0.f, 0.f, 0.f, 0.f};
  // sim[t][s], lane holds rows t=kc*4+r, col s=lr
  f32x4 sim = __builtin_amdgcn_mfma_f32_16x16x32_bf16(aq0, bk0, zero, 0, 0, 0);
  sim = __builtin_amdgcn_mfma_f32_16x16x32_bf16(aq1, bk1, sim, 0, 0, 0);
  // rq[t][j] = q . relk[j], two j-tiles (j = lr and 16+lr)
  bf16x8 rka0 = *(const bf16x8*)(relkS + lr * 72 + kc * 8);
  bf16x8 rka1 = *(const bf16x8*)(relkS + lr * 72 + 32 + kc * 8);
  bf16x8 rkb0 = *(const bf16x8*)(relkS + (16 + lr) * 72 + kc * 8);
  bf16x8 rkb1 = *(const bf16x8*)(relkS + (16 + lr) * 72 + 32 + kc * 8);
  f32x4 rqa = __builtin_amdgcn_mfma_f32_16x16x32_bf16(aq0, rka0, zero, 0, 0, 0);
  rqa = __builtin_amdgcn_mfma_f32_16x16x32_bf16(aq1, rka1, rqa, 0, 0, 0);
  f32x4 rqb = __builtin_amdgcn_mfma_f32_16x16x32_bf16(aq0, rkb0, zero, 0, 0, 0);
  rqb = __builtin_amdgcn_mfma_f32_16x16x32_bf16(aq1, rkb1, rqb, 0, 0, 0);
  #pragma unroll
  for (int r = 0; r < 4; ++r) {
    const int t = kc * 4 + r;
    const int j = lr - t + 16;                 // in [1,31], never clipped
    const int src = (l & 48) | (j & 15);       // same kc group, col j (or j-16)
    const float va = __shfl(rqa[r], src, 64);
    const float vb = __shfl(rqb[r], src, 64);
    const float rqv = (j < 16) ? va : vb;
    float sv = (sim[r] + rqv) * 0.125f;
    float m = sv;
    m = fmaxf(m, __shfl_xor(m, 1, 64));
    m = fmaxf(m, __shfl_xor(m, 2, 64));
    m = fmaxf(m, __shfl_xor(m, 4, 64));
    m = fmaxf(m, __shfl_xor(m, 8, 64));
    const float p = __expf(sv - m);
    float su = p;
    su += __shfl_xor(su, 1, 64);
    su += __shfl_xor(su, 2, 64);
    su += __shfl_xor(su, 4, 64);
    su += __shfl_xor(su, 8, 64);
    attnS[w][t * 17 + lr] = p / su;
  }
  __syncthreads();   // attn[t][s] complete (also orders same-wave LDS RAW)
  // Build PV A-frags: attn (k = s, zero for s>=16) and w2 (k = j, guarded gather)
  const float* aS = attnS[w];
  bf16x8 attnA, w2A;
  #pragma unroll
  for (int i = 0; i < 8; ++i) {
    const int s1 = kc * 8 + i;
    attnA[i] = (s1 < 16) ? (short)f2bf(aS[lr * 17 + s1]) : (short)0;
    const int s2 = s1 + lr - 16;               // = j + t - 16, row t = lr
    w2A[i] = (s2 >= 0 && s2 < 16) ? (short)f2bf(aS[lr * 17 + s2]) : (short)0;
  }
  #pragma unroll
  for (int dt = 0; dt < 4; ++dt) {
    // B-frags: col d' = lr (within d-tile), k contiguous
    bf16x8 vf  = *(const bf16x8*)(&vT[w][(dt * 16 + lr) * 24 + (kc & 1) * 8]);  // garbage*0 for kc>=2
    bf16x8 rvf = *(const bf16x8*)(&relvT[(dt * 16 + lr) * 40 + kc * 8]);
    f32x4 o = __builtin_amdgcn_mfma_f32_16x16x32_bf16(w2A, rvf, zero, 0, 0, 0);
    o = __builtin_amdgcn_mfma_f32_16x16x32_bf16(attnA, vf, o, 0, 0, 0);
    #pragma unroll
    for (int r = 0; r < 4; ++r) {
      const int t = kc * 4 + r;
      outA[(size_t)(rowBase + t) * 512 + h * 64 + dt * 16 + lr] = f2bf(o[r]);
    }
  }
}

// ---------------------------------------------------------------------------
extern "C" void kernel_launch(void* const* d_in, const int* in_sizes, int n_in,
                              void* d_out, int out_size, void* d_ws, size_t ws_size,
                              hipStream_t stream) {
  const float* x    = (const float*)d_in[0];
  const float* Wq   = (const float*)d_in[1];
  const float* Wk   = (const float*)d_in[2];
  const float* Wv   = (const float*)d_in[3];
  const float* Wo   = (const float*)d_in[4];
  const float* bo   = (const float*)d_in[5];
  const float* relk = (const float*)d_in[6];
  const float* relv = (const float*)d_in[7];

  char* ws = (char*)d_ws;
  uint16_t* qkv   = (uint16_t*)ws;                    // [32768][1536] bf16
  uint16_t* xbf   = (uint16_t*)(ws + 100663296);      // [32768][512] bf16
  uint16_t* WqkvT = (uint16_t*)(ws + 134217728);      // [1536][512] bf16 (B^T)
  uint16_t* WoT   = (uint16_t*)(ws + 135790592);      // [512][512] bf16 (B^T)
  uint16_t* attnO = xbf;                              // reuse: x_bf dead after GEMM1

  cast_kernel<<<8192, 256, 0, stream>>>(x, xbf, 2097152);
  dim3 tb(32, 8);
  transpose_cast<<<dim3(16, 16), tb, 0, stream>>>(Wq, WqkvT);
  transpose_cast<<<dim3(16, 16), tb, 0, stream>>>(Wk, WqkvT + 262144);
  transpose_cast<<<dim3(16, 16), tb, 0, stream>>>(Wv, WqkvT + 524288);
  transpose_cast<<<dim3(16, 16), tb, 0, stream>>>(Wo, WoT);
  // qkv = x_bf @ [Wq|Wk|Wv]   (M=32768, N=1536, K=512), bf16 out
  gemm_bt<1><<<dim3(12, 256), 256, 0, stream>>>(xbf, WqkvT, (void*)qkv, nullptr, 32768, 1536, 512);
  // attention (writes attn_out bf16 [32768][512])
  attn_kernel<<<4096, 256, 0, stream>>>(qkv, relk, relv, attnO);
  // out = attn_out @ Wo + bo  (fp32 out)
  gemm_bt<0><<<dim3(4, 256), 256, 0, stream>>>(attnO, WoT, d_out, bo, 32768, 512, 512);
}

// Round 2
// 150.248 us; speedup vs baseline: 1.1641x; 1.1641x over previous
//
#include <hip/hip_runtime.h>
#include <stdint.h>

// ---------------------------------------------------------------------------
// TemporalCrossAttention: x[2048,16,512] -> out[2048,16,512] (fp32 in/out)
// Pipeline: cast x->bf16 | transpose W->B^T bf16 | GEMM qkv | attn (MFMA) | GEMM out
// GEMM: 256x256 tile, 8 waves, BK=32 K-tiles, 4 LDS buffers, counted-vmcnt
// 8-phase-style schedule (T1+T2+T3+T4+T5 per cdna_hip_programming §5.5).
// Workspace layout (bytes):
//   [0, 100663296)            qkv bf16 [32768][1536]
//   [100663296, 134217728)    x_bf16 [32768][512]  (reused as attn_out after GEMM1)
//   [134217728, 135790592)    WqkvT bf16 [1536][512]
//   [135790592, 136314880)    WoT   bf16 [512][512]
// ---------------------------------------------------------------------------

using bf16x8 = __attribute__((ext_vector_type(8))) short;
using f32x4  = __attribute__((ext_vector_type(4))) float;

#define AS3P(p) ((__attribute__((address_space(3))) void*)(p))
#define AS1P(p) ((const __attribute__((address_space(1))) void*)(p))

__device__ __forceinline__ uint16_t f2bf(float f) {
  unsigned int x = __builtin_bit_cast(unsigned int, f);
  x += 0x7fffu + ((x >> 16) & 1u);
  return (uint16_t)(x >> 16);
}

// ---------------- cast x fp32 -> bf16 (8 elems/thread) ----------------
__global__ void cast_kernel(const float* __restrict__ in, uint16_t* __restrict__ out, int n8) {
  int i = blockIdx.x * 256 + threadIdx.x;
  if (i >= n8) return;
  float4 a = ((const float4*)in)[i * 2];
  float4 b = ((const float4*)in)[i * 2 + 1];
  uint4 r;
  r.x = (uint32_t)f2bf(a.x) | ((uint32_t)f2bf(a.y) << 16);
  r.y = (uint32_t)f2bf(a.z) | ((uint32_t)f2bf(a.w) << 16);
  r.z = (uint32_t)f2bf(b.x) | ((uint32_t)f2bf(b.y) << 16);
  r.w = (uint32_t)f2bf(b.z) | ((uint32_t)f2bf(b.w) << 16);
  ((uint4*)out)[i] = r;
}

// ------------- transpose-cast [512][512] f32 -> dst[n][k]=src[k][n] bf16 -------------
__global__ void transpose_cast(const float* __restrict__ src, uint16_t* __restrict__ dst) {
  __shared__ float tile[32][33];
  int tx = threadIdx.x, ty = threadIdx.y;           // (32,8)
  int c0 = blockIdx.x * 32, r0 = blockIdx.y * 32;
  #pragma unroll
  for (int k = 0; k < 4; ++k)
    tile[ty + 8 * k][tx] = src[(r0 + ty + 8 * k) * 512 + c0 + tx];
  __syncthreads();
  #pragma unroll
  for (int k = 0; k < 4; ++k)
    dst[(c0 + ty + 8 * k) * 512 + r0 + tx] = f2bf(tile[tx][ty + 8 * k]);
}

// ---------------- GEMM: C[M,N] = A[M,K] * B_T[N,K]^T  (bf16 in) ----------------
// 256x256 tile, 512 threads (8 waves = 2 wm x 4 wn), per-wave C block 128x64.
// K-tiles of BK=32; 4 LDS buffers (A 16KB + B 16KB each) rotate; prefetch
// distance 3 tiles; one counted s_waitcnt vmcnt(6) per tile.
// LDS swizzle (both sides): within a 128B row-pair, 16B chunk at logical
// (row,chunk) lives at pos = (((row&1)<<2)|chunk) ^ ((row>>1)&7).
template<int OUT_BF16, int KDIM>
__global__ __launch_bounds__(512, 2) void gemm256(
    const uint16_t* __restrict__ A, const uint16_t* __restrict__ B,
    void* __restrict__ C, const float* __restrict__ bias, int N, int nbx) {
  constexpr int NT = KDIM / 32;
  static_assert(NT >= 4, "need >=4 K-tiles");
  __shared__ __align__(16) uint16_t lds[4][2][8192];   // [buf][A/B][256*32], 128 KiB
  const int tid = threadIdx.x;
  const int w = tid >> 6, l = tid & 63;
  const int lr = l & 15, kc = l >> 4;
  const int wm = w >> 2, wn = w & 3;
  // T1: XCD-chunked bijective swizzle (gridDim.x % 8 == 0 for both launches)
  const int cpx = gridDim.x >> 3;
  const int id = blockIdx.x;
  const int swz = (id & 7) * cpx + (id >> 3);
  const int by = swz / nbx, bx = swz - by * nbx;
  const int mBase = by * 256, nBase = bx * 256;
  // staging source precompute (pre-swizzled global address, linear LDS dest)
  const int g8 = l >> 3;
  const int sub = (l & 7) ^ g8;
  const int srow = w * 32 + g8 * 2 + (sub >> 2);       // + j*16 for second load
  const int scol = (sub & 3) * 8;
  const uint16_t* gA0 = A + (size_t)(mBase + srow) * KDIM + scol;
  const uint16_t* gA1 = gA0 + 16 * KDIM;
  const uint16_t* gB0 = B + (size_t)(nBase + srow) * KDIM + scol;
  const uint16_t* gB1 = gB0 + 16 * KDIM;
  // ds_read byte offsets within one 16KB matrix buffer (swizzled)
  int offA[8], offB[4];
  #pragma unroll
  for (int m = 0; m < 8; ++m) {
    int row = wm * 128 + m * 16 + lr;
    int rp = row >> 1, sb = ((row & 1) << 2) | kc;
    offA[m] = rp * 128 + (sb ^ (rp & 7)) * 16;
  }
  #pragma unroll
  for (int n = 0; n < 4; ++n) {
    int row = wn * 64 + n * 16 + lr;
    int rp = row >> 1, sb = ((row & 1) << 2) | kc;
    offB[n] = rp * 128 + (sb ^ (rp & 7)) * 16;
  }
  f32x4 acc[8][4] = {};
  // prologue: stage tiles 0,1,2 (issue order A,A,B,B per tile)
  #pragma unroll
  for (int pt = 0; pt < 3; ++pt) {
    uint16_t* dA = &lds[pt][0][w * 1024];
    uint16_t* dB = &lds[pt][1][w * 1024];
    __builtin_amdgcn_global_load_lds(AS1P(gA0 + pt * 32), AS3P(dA),       16, 0, 0);
    __builtin_amdgcn_global_load_lds(AS1P(gA1 + pt * 32), AS3P(dA + 512), 16, 0, 0);
    __builtin_amdgcn_global_load_lds(AS1P(gB0 + pt * 32), AS3P(dB),       16, 0, 0);
    __builtin_amdgcn_global_load_lds(AS1P(gB1 + pt * 32), AS3P(dB + 512), 16, 0, 0);
  }
  asm volatile("s_waitcnt vmcnt(8)" ::: "memory");   // tile 0 resident
  __builtin_amdgcn_s_barrier();

  #pragma unroll 4
  for (int t = 0; t < NT; ++t) {
    const int bi = t & 3;
    const int si = (t + 3) & 3;
    const char* bufA = (const char*)&lds[bi][0][0];
    const char* bufB = (const char*)&lds[bi][1][0];
    // ---------------- phase 1 ----------------
    if (t + 3 < NT) {   // stage A(t+3) into buffer freed at end of tile t-1
      uint16_t* dA = &lds[si][0][w * 1024];
      __builtin_amdgcn_global_load_lds(AS1P(gA0 + (t + 3) * 32), AS3P(dA),       16, 0, 0);
      __builtin_amdgcn_global_load_lds(AS1P(gA1 + (t + 3) * 32), AS3P(dA + 512), 16, 0, 0);
    }
    // counted wait: confirms tile t+1 fully resident (per-wave), propagated
    // cross-wave by the barrier below, before any wave reads tile t+1.
    if (t + 3 < NT)       asm volatile("s_waitcnt vmcnt(6)" ::: "memory");
    else if (t + 3 == NT) asm volatile("s_waitcnt vmcnt(4)" ::: "memory");
    else if (t + 2 == NT) asm volatile("s_waitcnt vmcnt(0)" ::: "memory");
    bf16x8 a0 = *(const bf16x8*)(bufA + offA[0]);
    bf16x8 a1 = *(const bf16x8*)(bufA + offA[1]);
    bf16x8 a2 = *(const bf16x8*)(bufA + offA[2]);
    bf16x8 a3 = *(const bf16x8*)(bufA + offA[3]);
    bf16x8 b0 = *(const bf16x8*)(bufB + offB[0]);
    bf16x8 b1 = *(const bf16x8*)(bufB + offB[1]);
    bf16x8 b2 = *(const bf16x8*)(bufB + offB[2]);
    bf16x8 b3 = *(const bf16x8*)(bufB + offB[3]);
    __builtin_amdgcn_sched_barrier(0);
    __builtin_amdgcn_s_barrier();
    asm volatile("s_waitcnt lgkmcnt(0)" ::: "memory");
    __builtin_amdgcn_sched_barrier(0);
    __builtin_amdgcn_s_setprio(1);
    acc[0][0] = __builtin_amdgcn_mfma_f32_16x16x32_bf16(a0, b0, acc[0][0], 0, 0, 0);
    acc[0][1] = __builtin_amdgcn_mfma_f32_16x16x32_bf16(a0, b1, acc[0][1], 0, 0, 0);
    acc[0][2] = __builtin_amdgcn_mfma_f32_16x16x32_bf16(a0, b2, acc[0][2], 0, 0, 0);
    acc[0][3] = __builtin_amdgcn_mfma_f32_16x16x32_bf16(a0, b3, acc[0][3], 0, 0, 0);
    acc[1][0] = __builtin_amdgcn_mfma_f32_16x16x32_bf16(a1, b0, acc[1][0], 0, 0, 0);
    acc[1][1] = __builtin_amdgcn_mfma_f32_16x16x32_bf16(a1, b1, acc[1][1], 0, 0, 0);
    acc[1][2] = __builtin_amdgcn_mfma_f32_16x16x32_bf16(a1, b2, acc[1][2], 0, 0, 0);
    acc[1][3] = __builtin_amdgcn_mfma_f32_16x16x32_bf16(a1, b3, acc[1][3], 0, 0, 0);
    acc[2][0] = __builtin_amdgcn_mfma_f32_16x16x32_bf16(a2, b0, acc[2][0], 0, 0, 0);
    acc[2][1] = __builtin_amdgcn_mfma_f32_16x16x32_bf16(a2, b1, acc[2][1], 0, 0, 0);
    acc[2][2] = __builtin_amdgcn_mfma_f32_16x16x32_bf16(a2, b2, acc[2][2], 0, 0, 0);
    acc[2][3] = __builtin_amdgcn_mfma_f32_16x16x32_bf16(a2, b3, acc[2][3], 0, 0, 0);
    acc[3][0] = __builtin_amdgcn_mfma_f32_16x16x32_bf16(a3, b0, acc[3][0], 0, 0, 0);
    acc[3][1] = __builtin_amdgcn_mfma_f32_16x16x32_bf16(a3, b1, acc[3][1], 0, 0, 0);
    acc[3][2] = __builtin_amdgcn_mfma_f32_16x16x32_bf16(a3, b2, acc[3][2], 0, 0, 0);
    acc[3][3] = __builtin_amdgcn_mfma_f32_16x16x32_bf16(a3, b3, acc[3][3], 0, 0, 0);
    __builtin_amdgcn_s_setprio(0);
    __builtin_amdgcn_sched_barrier(0);
    __builtin_amdgcn_s_barrier();
    // ---------------- phase 2 ----------------
    if (t + 3 < NT) {   // stage B(t+3)
      uint16_t* dB = &lds[si][1][w * 1024];
      __builtin_amdgcn_global_load_lds(AS1P(gB0 + (t + 3) * 32), AS3P(dB),       16, 0, 0);
      __builtin_amdgcn_global_load_lds(AS1P(gB1 + (t + 3) * 32), AS3P(dB + 512), 16, 0, 0);
    }
    bf16x8 a4 = *(const bf16x8*)(bufA + offA[4]);
    bf16x8 a5 = *(const bf16x8*)(bufA + offA[5]);
    bf16x8 a6 = *(const bf16x8*)(bufA + offA[6]);
    bf16x8 a7 = *(const bf16x8*)(bufA + offA[7]);
    __builtin_amdgcn_sched_barrier(0);
    __builtin_amdgcn_s_barrier();
    asm volatile("s_waitcnt lgkmcnt(0)" ::: "memory");
    __builtin_amdgcn_sched_barrier(0);
    __builtin_amdgcn_s_setprio(1);
    acc[4][0] = __builtin_amdgcn_mfma_f32_16x16x32_bf16(a4, b0, acc[4][0], 0, 0, 0);
    acc[4][1] = __builtin_amdgcn_mfma_f32_16x16x32_bf16(a4, b1, acc[4][1], 0, 0, 0);
    acc[4][2] = __builtin_amdgcn_mfma_f32_16x16x32_bf16(a4, b2, acc[4][2], 0, 0, 0);
    acc[4][3] = __builtin_amdgcn_mfma_f32_16x16x32_bf16(a4, b3, acc[4][3], 0, 0, 0);
    acc[5][0] = __builtin_amdgcn_mfma_f32_16x16x32_bf16(a5, b0, acc[5][0], 0, 0, 0);
    acc[5][1] = __builtin_amdgcn_mfma_f32_16x16x32_bf16(a5, b1, acc[5][1], 0, 0, 0);
    acc[5][2] = __builtin_amdgcn_mfma_f32_16x16x32_bf16(a5, b2, acc[5][2], 0, 0, 0);
    acc[5][3] = __builtin_amdgcn_mfma_f32_16x16x32_bf16(a5, b3, acc[5][3], 0, 0, 0);
    acc[6][0] = __builtin_amdgcn_mfma_f32_16x16x32_bf16(a6, b0, acc[6][0], 0, 0, 0);
    acc[6][1] = __builtin_amdgcn_mfma_f32_16x16x32_bf16(a6, b1, acc[6][1], 0, 0, 0);
    acc[6][2] = __builtin_amdgcn_mfma_f32_16x16x32_bf16(a6, b2, acc[6][2], 0, 0, 0);
    acc[6][3] = __builtin_amdgcn_mfma_f32_16x16x32_bf16(a6, b3, acc[6][3], 0, 0, 0);
    acc[7][0] = __builtin_amdgcn_mfma_f32_16x16x32_bf16(a7, b0, acc[7][0], 0, 0, 0);
    acc[7][1] = __builtin_amdgcn_mfma_f32_16x16x32_bf16(a7, b1, acc[7][1], 0, 0, 0);
    acc[7][2] = __builtin_amdgcn_mfma_f32_16x16x32_bf16(a7, b2, acc[7][2], 0, 0, 0);
    acc[7][3] = __builtin_amdgcn_mfma_f32_16x16x32_bf16(a7, b3, acc[7][3], 0, 0, 0);
    __builtin_amdgcn_s_setprio(0);
    __builtin_amdgcn_sched_barrier(0);
    __builtin_amdgcn_s_barrier();
  }
  // epilogue: C/D layout col = lane&15, row = (lane>>4)*4 + reg
  #pragma unroll
  for (int m = 0; m < 8; ++m)
    #pragma unroll
    for (int n = 0; n < 4; ++n) {
      const int col = nBase + wn * 64 + n * 16 + lr;
      #pragma unroll
      for (int r = 0; r < 4; ++r) {
        const int row = mBase + wm * 128 + m * 16 + kc * 4 + r;
        if (OUT_BF16) ((uint16_t*)C)[(size_t)row * N + col] = f2bf(acc[m][n][r]);
        else          ((float*)C)[(size_t)row * N + col]    = acc[m][n][r] + bias[col];
      }
    }
}

// ---------------- attention: one wave per (b,h) ----------------
__global__ __launch_bounds__(256) void attn_kernel(
    const uint16_t* __restrict__ qkv,
    const float* __restrict__ relk, const float* __restrict__ relv,
    uint16_t* __restrict__ outA) {
  __shared__ __align__(16) uint16_t relkS[33 * 72];
  __shared__ __align__(16) uint16_t relvT[64 * 40];
  __shared__ __align__(16) uint16_t vT[4][64 * 24];
  __shared__ float attnS[4][16 * 17];
  const int tid = threadIdx.x;
  for (int e = tid; e < 33 * 64; e += 256) {
    int j = e >> 6, d = e & 63;
    relkS[j * 72 + d] = f2bf(relk[e]);
    relvT[d * 40 + j] = f2bf(relv[e]);
  }
  const int w = tid >> 6, l = tid & 63;
  const int bh = blockIdx.x * 4 + w;
  const int b = bh >> 3, h = bh & 7;
  const int rowBase = b * 16;
  const int lr = l & 15, kc = l >> 4;
  const uint16_t* qrow = qkv + (size_t)(rowBase + lr) * 1536 + h * 64;
  bf16x8 aq0 = *(const bf16x8*)(qrow + kc * 8);
  bf16x8 aq1 = *(const bf16x8*)(qrow + 32 + kc * 8);
  const uint16_t* krow = qrow + 512;
  bf16x8 bk0 = *(const bf16x8*)(krow + kc * 8);
  bf16x8 bk1 = *(const bf16x8*)(krow + 32 + kc * 8);
  {
    const int s = l >> 2, dg = l & 3;
    const uint16_t* vrow = qkv + (size_t)(rowBase + s) * 1536 + 1024 + h * 64 + dg * 16;
    uint4 v0 = *(const uint4*)vrow;
    uint4 v1 = *(const uint4*)(vrow + 8);
    uint16_t tmp[16];
    *(uint4*)(tmp) = v0; *(uint4*)(tmp + 8) = v1;
    #pragma unroll
    for (int i = 0; i < 16; ++i)
      vT[w][(dg * 16 + i) * 24 + s] = tmp[i];
  }
  __syncthreads();
  const f32x4 zero = {0.f, 0.f, 0.f, 0.f};
  f32x4 sim = __builtin_amdgcn_mfma_f32_16x16x32_bf16(aq0, bk0, zero, 0, 0, 0);
  sim = __builtin_amdgcn_mfma_f32_16x16x32_bf16(aq1, bk1, sim, 0, 0, 0);
  bf16x8 rka0 = *(const bf16x8*)(relkS + lr * 72 + kc * 8);
  bf16x8 rka1 = *(const bf16x8*)(relkS + lr * 72 + 32 + kc * 8);
  bf16x8 rkb0 = *(const bf16x8*)(relkS + (16 + lr) * 72 + kc * 8);
  bf16x8 rkb1 = *(const bf16x8*)(relkS + (16 + lr) * 72 + 32 + kc * 8);
  f32x4 rqa = __builtin_amdgcn_mfma_f32_16x16x32_bf16(aq0, rka0, zero, 0, 0, 0);
  rqa = __builtin_amdgcn_mfma_f32_16x16x32_bf16(aq1, rka1, rqa, 0, 0, 0);
  f32x4 rqb = __builtin_amdgcn_mfma_f32_16x16x32_bf16(aq0, rkb0, zero, 0, 0, 0);
  rqb = __builtin_amdgcn_mfma_f32_16x16x32_bf16(aq1, rkb1, rqb, 0, 0, 0);
  #pragma unroll
  for (int r = 0; r < 4; ++r) {
    const int t = kc * 4 + r;
    const int j = lr - t + 16;
    const int src = (l & 48) | (j & 15);
    const float va = __shfl(rqa[r], src, 64);
    const float vb = __shfl(rqb[r], src, 64);
    const float rqv = (j < 16) ? va : vb;
    float sv = (sim[r] + rqv) * 0.125f;
    float m = sv;
    m = fmaxf(m, __shfl_xor(m, 1, 64));
    m = fmaxf(m, __shfl_xor(m, 2, 64));
    m = fmaxf(m, __shfl_xor(m, 4, 64));
    m = fmaxf(m, __shfl_xor(m, 8, 64));
    const float p = __expf(sv - m);
    float su = p;
    su += __shfl_xor(su, 1, 64);
    su += __shfl_xor(su, 2, 64);
    su += __shfl_xor(su, 4, 64);
    su += __shfl_xor(su, 8, 64);
    attnS[w][t * 17 + lr] = p / su;
  }
  __syncthreads();
  const float* aS = attnS[w];
  bf16x8 attnA, w2A;
  #pragma unroll
  for (int i = 0; i < 8; ++i) {
    const int s1 = kc * 8 + i;
    attnA[i] = (s1 < 16) ? (short)f2bf(aS[lr * 17 + s1]) : (short)0;
    const int s2 = s1 + lr - 16;
    w2A[i] = (s2 >= 0 && s2 < 16) ? (short)f2bf(aS[lr * 17 + s2]) : (short)0;
  }
  #pragma unroll
  for (int dt = 0; dt < 4; ++dt) {
    bf16x8 vf  = *(const bf16x8*)(&vT[w][(dt * 16 + lr) * 24 + (kc & 1) * 8]);
    bf16x8 rvf = *(const bf16x8*)(&relvT[(dt * 16 + lr) * 40 + kc * 8]);
    f32x4 o = __builtin_amdgcn_mfma_f32_16x16x32_bf16(w2A, rvf, zero, 0, 0, 0);
    o = __builtin_amdgcn_mfma_f32_16x16x32_bf16(attnA, vf, o, 0, 0, 0);
    #pragma unroll
    for (int r = 0; r < 4; ++r) {
      const int t = kc * 4 + r;
      outA[(size_t)(rowBase + t) * 512 + h * 64 + dt * 16 + lr] = f2bf(o[r]);
    }
  }
}

// ---------------------------------------------------------------------------
extern "C" void kernel_launch(void* const* d_in, const int* in_sizes, int n_in,
                              void* d_out, int out_size, void* d_ws, size_t ws_size,
                              hipStream_t stream) {
  const float* x    = (const float*)d_in[0];
  const float* Wq   = (const float*)d_in[1];
  const float* Wk   = (const float*)d_in[2];
  const float* Wv   = (const float*)d_in[3];
  const float* Wo   = (const float*)d_in[4];
  const float* bo   = (const float*)d_in[5];
  const float* relk = (const float*)d_in[6];
  const float* relv = (const float*)d_in[7];

  char* ws = (char*)d_ws;
  uint16_t* qkv   = (uint16_t*)ws;                    // [32768][1536] bf16
  uint16_t* xbf   = (uint16_t*)(ws + 100663296);      // [32768][512] bf16
  uint16_t* WqkvT = (uint16_t*)(ws + 134217728);      // [1536][512] bf16 (B^T)
  uint16_t* WoT   = (uint16_t*)(ws + 135790592);      // [512][512] bf16 (B^T)
  uint16_t* attnO = xbf;                              // reuse: x_bf dead after GEMM1

  cast_kernel<<<8192, 256, 0, stream>>>(x, xbf, 2097152);
  dim3 tb(32, 8);
  transpose_cast<<<dim3(16, 16), tb, 0, stream>>>(Wq, WqkvT);
  transpose_cast<<<dim3(16, 16), tb, 0, stream>>>(Wk, WqkvT + 262144);
  transpose_cast<<<dim3(16, 16), tb, 0, stream>>>(Wv, WqkvT + 524288);
  transpose_cast<<<dim3(16, 16), tb, 0, stream>>>(Wo, WoT);
  // qkv = x_bf @ [Wq|Wk|Wv]   (M=32768, N=1536, K=512), bf16 out; grid 128*6
  gemm256<1, 512><<<dim3(768), dim3(512), 0, stream>>>(xbf, WqkvT, (void*)qkv, nullptr, 1536, 6);
  // attention (writes attn_out bf16 [32768][512])
  attn_kernel<<<4096, 256, 0, stream>>>(qkv, relk, relv, attnO);
  // out = attn_out @ Wo + bo  (fp32 out, M=32768, N=512, K=512); grid 128*2
  gemm256<0, 512><<<dim3(256), dim3(512), 0, stream>>>(attnO, WoT, d_out, bo, 512, 2);
}